// Round 7
// baseline (594.929 us; speedup 1.0000x reference)
//
#include <hip/hip_runtime.h>
#include <math.h>

#define DIM 1024
#define DSTATE 16
#define DCONV 4
#define BATCH 2
#define TLEN 4096
#define NC 128           // time chunks
#define LC (TLEN / NC)   // 32 steps per chunk

typedef short s16x4 __attribute__((ext_vector_type(4)));
typedef short s16x8 __attribute__((ext_vector_type(8)));
typedef float f32x4 __attribute__((ext_vector_type(4)));
typedef float f32x16 __attribute__((ext_vector_type(16)));

__device__ __forceinline__ unsigned short f32_to_bf16(float f) {
    unsigned int u = __float_as_uint(f);
    u += 0x7fffu + ((u >> 16) & 1u);
    return (unsigned short)(u >> 16);
}
__device__ __forceinline__ float bf16_to_f32(unsigned short s) {
    return __uint_as_float(((unsigned int)s) << 16);
}

__device__ __forceinline__ void async16(const void* g, void* l) {
    __builtin_amdgcn_global_load_lds(
        (const __attribute__((address_space(1))) void*)g,
        (__attribute__((address_space(3))) void*)l, 16, 0, 0);
}

// Strided index into dead x-half columns of xz (P/S chunk-scan scratch).
__device__ __forceinline__ size_t ps_addr(size_t i) {
    return ((i >> 10) << 11) | (i & 1023);
}

// ---------------------------------------------------------------------------
// Split-bf16 MFMA GEMM: C[M,N] = (Ah+Al)[M,K] @ (Bh+Bl)^T[N,K]
// 128x128 tile, BK=32, 256 threads (4 waves, 2x2 of 64x64), 32x32x16 MFMA
// (wave tile = 2x2 of 32x32). 16 B LDS chunks XOR-swizzled by ((row>>1)&3).
// EPI: 0 = plain store, 1 = softplus(acc+bias[n]).
// NOTE (R6 post-mortem): keep grids at integer blocks/CU — N=1152 (576
// blocks = 2.25/CU) pinned this kernel at 117.7 us regardless of everything.
// ---------------------------------------------------------------------------
template <int EPI>
__global__ __launch_bounds__(256) void gemm_bf16s(
    const unsigned short* __restrict__ Ah, const unsigned short* __restrict__ Al,
    const unsigned short* __restrict__ Bh, const unsigned short* __restrict__ Bl,
    const float* __restrict__ bias, float* __restrict__ C,
    int M, int N, int K)
{
    __shared__ unsigned short sAh[128][32];
    __shared__ unsigned short sAl[128][32];
    __shared__ unsigned short sBh[128][32];
    __shared__ unsigned short sBl[128][32];

    const int tid  = threadIdx.x;
    const int lane = tid & 63;
    const int w    = tid >> 6;
    const int wm   = (w >> 1) * 64;
    const int wn   = (w & 1) * 64;
    const int m0   = blockIdx.y * 128;
    const int n0   = blockIdx.x * 128;

    f32x16 acc[2][2];
#pragma unroll
    for (int i = 0; i < 2; ++i)
#pragma unroll
        for (int j = 0; j < 2; ++j)
#pragma unroll
            for (int r = 0; r < 16; ++r) acc[i][j][r] = 0.f;

    const int srow  = w * 16 + (lane >> 2);
    const int skoff = (((lane & 3) ^ ((lane >> 3) & 3)) * 8);
    const size_t aRow0 = (size_t)(m0 + srow) * K;
    const size_t aRow1 = (size_t)(m0 + srow + 64) * K;
    const size_t bRow0 = (size_t)(n0 + srow) * K;
    const size_t bRow1 = (size_t)(n0 + srow + 64) * K;

    const int frow = lane & 31;
    const int fkh  = lane >> 5;
    const int fsw  = (lane >> 1) & 3;

    for (int k0 = 0; k0 < K; k0 += 32) {
        __syncthreads();
        async16(&Ah[aRow0 + k0 + skoff], &sAh[w * 16][0]);
        async16(&Ah[aRow1 + k0 + skoff], &sAh[64 + w * 16][0]);
        async16(&Al[aRow0 + k0 + skoff], &sAl[w * 16][0]);
        async16(&Al[aRow1 + k0 + skoff], &sAl[64 + w * 16][0]);
        async16(&Bh[bRow0 + k0 + skoff], &sBh[w * 16][0]);
        async16(&Bh[bRow1 + k0 + skoff], &sBh[64 + w * 16][0]);
        async16(&Bl[bRow0 + k0 + skoff], &sBl[w * 16][0]);
        async16(&Bl[bRow1 + k0 + skoff], &sBl[64 + w * 16][0]);
        __syncthreads();

#pragma unroll
        for (int ks = 0; ks < 2; ++ks) {
            const int pc = (((ks << 1) | fkh) ^ fsw) << 3;
            s16x8 fah[2], fal[2], fbh[2], fbl[2];
#pragma unroll
            for (int i = 0; i < 2; ++i) {
                fah[i] = *(const s16x8*)&sAh[wm + i * 32 + frow][pc];
                fal[i] = *(const s16x8*)&sAl[wm + i * 32 + frow][pc];
                fbh[i] = *(const s16x8*)&sBh[wn + i * 32 + frow][pc];
                fbl[i] = *(const s16x8*)&sBl[wn + i * 32 + frow][pc];
            }
#pragma unroll
            for (int mt = 0; mt < 2; ++mt)
#pragma unroll
                for (int nt = 0; nt < 2; ++nt) {
                    acc[mt][nt] = __builtin_amdgcn_mfma_f32_32x32x16_bf16(
                        fah[mt], fbh[nt], acc[mt][nt], 0, 0, 0);
                    acc[mt][nt] = __builtin_amdgcn_mfma_f32_32x32x16_bf16(
                        fah[mt], fbl[nt], acc[mt][nt], 0, 0, 0);
                    acc[mt][nt] = __builtin_amdgcn_mfma_f32_32x32x16_bf16(
                        fal[mt], fbh[nt], acc[mt][nt], 0, 0, 0);
                }
        }
    }

    // C/D layout (32x32): col = lane&31, row = (reg&3) + 8*(reg>>2) + 4*(lane>>5)
    const int ecol  = lane & 31;
    const int erow4 = (lane >> 5) * 4;
#pragma unroll
    for (int mt = 0; mt < 2; ++mt)
#pragma unroll
        for (int nt = 0; nt < 2; ++nt) {
            const int col = n0 + wn + nt * 32 + ecol;
            const float bv = (EPI == 1) ? bias[col] : 0.f;
#pragma unroll
            for (int r = 0; r < 16; ++r) {
                const int row = m0 + wm + mt * 32 + (r & 3) + 8 * (r >> 2) + erow4;
                float v = acc[mt][nt][r];
                if (EPI == 1) {
                    v += bv;
                    v = (v > 20.f) ? v : log1pf(__expf(v));
                }
                C[(size_t)row * N + col] = v;
            }
        }
}

// ---------------------------------------------------------------------------
// BC = x_in(B*T, DIM) @ W_x(DIM, 2*DSTATE)   (f32, proven R2 kernel)
// ---------------------------------------------------------------------------
__global__ __launch_bounds__(256) void bc_kernel(
    const float* __restrict__ x_in, const float* __restrict__ W_x,
    float* __restrict__ BC)
{
    int n = threadIdx.x & 31;
    int ml = threadIdx.x >> 5;
    size_t m = (size_t)blockIdx.x * 8 + ml;
    const float* xr = &x_in[m * DIM];
    float acc = 0.f;
#pragma unroll 4
    for (int k = 0; k < DIM; ++k) {
        acc = fmaf(xr[k], W_x[k * (2 * DSTATE) + n], acc);
    }
    BC[m * (2 * DSTATE) + n] = acc;
}

// ---------------------------------------------------------------------------
// Unified prep: weight transpose-splits + input x split, one launch.
// Blocks [0,2048): W_in; [2048,3072): W_dt; [3072,4096): W_out;
// [4096,12288): x split (4 elems/thread).
// ---------------------------------------------------------------------------
__device__ __forceinline__ void tsplit(
    const float* __restrict__ W, unsigned short* __restrict__ Th,
    unsigned short* __restrict__ Tl, int Kdim, int Ndim, int bx, int by,
    int tid, float (*tile)[33])
{
    const int n0 = bx * 32;
    const int k0 = by * 32;
    const int tx = tid & 31;
    const int ty = tid >> 5;
    for (int r = ty; r < 32; r += 8)
        tile[r][tx] = W[(size_t)(k0 + r) * Ndim + n0 + tx];
    __syncthreads();
    for (int r = ty; r < 32; r += 8) {
        float v = tile[tx][r];
        unsigned short hv = f32_to_bf16(v);
        size_t o = (size_t)(n0 + r) * Kdim + k0 + tx;
        Th[o] = hv;
        Tl[o] = f32_to_bf16(v - bf16_to_f32(hv));
    }
}

__global__ __launch_bounds__(256) void prep_kernel(
    const float* __restrict__ x, const float* __restrict__ W_in,
    const float* __restrict__ W_dt, const float* __restrict__ W_out,
    unsigned short* __restrict__ xh, unsigned short* __restrict__ xl,
    unsigned short* __restrict__ WinTh, unsigned short* __restrict__ WinTl,
    unsigned short* __restrict__ WdtTh, unsigned short* __restrict__ WdtTl,
    unsigned short* __restrict__ WoutTh, unsigned short* __restrict__ WoutTl)
{
    __shared__ float tile[32][33];
    const int tid = threadIdx.x;
    const int blk = blockIdx.x;
    if (blk < 2048) {
        tsplit(W_in, WinTh, WinTl, 1024, 2048, blk & 63, blk >> 6, tid, tile);
    } else if (blk < 3072) {
        const int b2 = blk - 2048;
        tsplit(W_dt, WdtTh, WdtTl, 1024, 1024, b2 & 31, b2 >> 5, tid, tile);
    } else if (blk < 4096) {
        const int b2 = blk - 3072;
        tsplit(W_out, WoutTh, WoutTl, 1024, 1024, b2 & 31, b2 >> 5, tid, tile);
    } else {
        const size_t i = ((size_t)(blk - 4096) * 256 + tid) * 4;
        f32x4 v = *(const f32x4*)&x[i];
        s16x4 h, l;
#pragma unroll
        for (int j = 0; j < 4; ++j) {
            unsigned short hv = f32_to_bf16(v[j]);
            h[j] = (short)hv;
            l[j] = (short)f32_to_bf16(v[j] - bf16_to_f32(hv));
        }
        *(s16x4*)&xh[i] = h;
        *(s16x4*)&xl[i] = l;
    }
}

// ---------------------------------------------------------------------------
// Depthwise causal conv (window 4) + bias + SiLU; 4 d-channels per thread;
// writes f32 + bf16 hi/lo.
// ---------------------------------------------------------------------------
__global__ __launch_bounds__(256) void conv_silu_kernel(
    const float* __restrict__ xz, const float* __restrict__ conv_w,
    const float* __restrict__ conv_b, float* __restrict__ x_in,
    unsigned short* __restrict__ xh, unsigned short* __restrict__ xl)
{
    const size_t idx4 = ((size_t)blockIdx.x * 256 + threadIdx.x) * 4;
    const int d = (int)(idx4 & (DIM - 1));
    const size_t bt = idx4 >> 10;
    const int t = (int)(bt & (TLEN - 1));

    f32x4 acc = *(const f32x4*)&conv_b[d];
    f32x4 w0 = *(const f32x4*)&conv_w[(d + 0) * DCONV];
    f32x4 w1 = *(const f32x4*)&conv_w[(d + 1) * DCONV];
    f32x4 w2 = *(const f32x4*)&conv_w[(d + 2) * DCONV];
    f32x4 w3 = *(const f32x4*)&conv_w[(d + 3) * DCONV];
#pragma unroll
    for (int k = 0; k < DCONV; ++k) {
        const int tt = t - (DCONV - 1) + k;
        if (tt >= 0) {
            f32x4 xv = *(const f32x4*)&xz[(bt - (DCONV - 1) + k) * (2 * DIM) + d];
            acc.x = fmaf(xv.x, w0[k], acc.x);
            acc.y = fmaf(xv.y, w1[k], acc.y);
            acc.z = fmaf(xv.z, w2[k], acc.z);
            acc.w = fmaf(xv.w, w3[k], acc.w);
        }
    }
    f32x4 s;
    s16x4 h, l;
#pragma unroll
    for (int j = 0; j < 4; ++j) {
        s[j] = acc[j] / (1.f + __expf(-acc[j]));
        unsigned short hv = f32_to_bf16(s[j]);
        h[j] = (short)hv;
        l[j] = (short)f32_to_bf16(s[j] - bf16_to_f32(hv));
    }
    *(f32x4*)&x_in[idx4] = s;
    *(s16x4*)&xh[idx4] = h;
    *(s16x4*)&xl[idx4] = l;
}

// ---------------------------------------------------------------------------
// Scan pass A: one lane per (b,d); h[16] in VGPRs; local scan from h=0.
// Stores S = h_local_end[16], P = exp(A_n * sum_dt). B staged in LDS.
// ---------------------------------------------------------------------------
__global__ __launch_bounds__(256) void scan_pass_a(
    const float* __restrict__ dt, const float* __restrict__ BC,
    const float* __restrict__ x_in, const float* __restrict__ A_log,
    float* __restrict__ Pb, float* __restrict__ Sb)
{
    __shared__ float sB[LC][DSTATE];
    const int tid = threadIdx.x;
    int blk = blockIdx.x;
    const int dt4 = blk & 3;  blk >>= 2;
    const int c = blk & (NC - 1); blk >>= 7;
    const int b = blk;
    const int d = dt4 * 256 + tid;
    const size_t base = (size_t)b * TLEN + (size_t)c * LC;

    if (tid < LC * DSTATE / 4) {
        const int row = tid >> 2, c4 = tid & 3;
        *(f32x4*)&sB[row][c4 * 4] =
            *(const f32x4*)&BC[(base + row) * (2 * DSTATE) + c4 * 4];
    }

    float A[DSTATE];
#pragma unroll
    for (int q = 0; q < 4; ++q) {
        f32x4 v = *(const f32x4*)&A_log[(size_t)d * DSTATE + q * 4];
        A[q * 4 + 0] = -__expf(v.x); A[q * 4 + 1] = -__expf(v.y);
        A[q * 4 + 2] = -__expf(v.z); A[q * 4 + 3] = -__expf(v.w);
    }
    __syncthreads();

    float h[DSTATE];
#pragma unroll
    for (int n = 0; n < DSTATE; ++n) h[n] = 0.f;
    float sdt = 0.f;

    for (int t = 0; t < LC; ++t) {
        const float dtv = dt[(base + t) * DIM + d];
        const float xv  = x_in[(base + t) * DIM + d];
        sdt += dtv;
        const float dbx = dtv * xv;
#pragma unroll
        for (int n = 0; n < DSTATE; ++n) {
            const float a = __expf(dtv * A[n]);
            h[n] = fmaf(a, h[n], dbx * sB[t][n]);
        }
    }

    const size_t po = ps_addr((((size_t)c * BATCH + b) * DIM + d) * DSTATE);
#pragma unroll
    for (int q = 0; q < 4; ++q) {
        f32x4 pv;
        pv.x = __expf(A[q * 4 + 0] * sdt);
        pv.y = __expf(A[q * 4 + 1] * sdt);
        pv.z = __expf(A[q * 4 + 2] * sdt);
        pv.w = __expf(A[q * 4 + 3] * sdt);
        *(f32x4*)&Pb[po + q * 4] = pv;
        *(f32x4*)&Sb[po + q * 4] = *(f32x4*)&h[q * 4];
    }
}

// ---------------------------------------------------------------------------
// Scan pass B: per (b,d,n): sequential combine over NC chunks.
// ---------------------------------------------------------------------------
__global__ __launch_bounds__(256) void scan_pass_b(
    float* __restrict__ Pb, const float* __restrict__ Sb)
{
    const size_t idx = (size_t)blockIdx.x * 256 + threadIdx.x;  // B*DIM*16
    float h = 0.f;
#pragma unroll 4
    for (int c = 0; c < NC; ++c) {
        const size_t o = (size_t)c * (BATCH * DIM * DSTATE) + idx;
        const size_t a = ps_addr(o);
        const float p = Pb[a];
        const float s = Sb[a];
        Pb[a] = h;
        h = fmaf(p, h, s);
    }
}

// ---------------------------------------------------------------------------
// Scan pass C: one lane per (b,d); seeded local scan; y = sum_n h*C + D*x;
// fused z-gate; writes y as bf16 hi/lo. B,C staged in LDS.
// ---------------------------------------------------------------------------
__global__ __launch_bounds__(256) void scan_pass_c(
    const float* __restrict__ dt, const float* __restrict__ BC,
    const float* __restrict__ xz, const float* __restrict__ A_log,
    const float* __restrict__ D_param, const float* __restrict__ Hin,
    const float* __restrict__ x_in,
    unsigned short* __restrict__ yh, unsigned short* __restrict__ yl)
{
    __shared__ float sB[LC][DSTATE];
    __shared__ float sC[LC][DSTATE];
    const int tid = threadIdx.x;
    int blk = blockIdx.x;
    const int dt4 = blk & 3;  blk >>= 2;
    const int c = blk & (NC - 1); blk >>= 7;
    const int b = blk;
    const int d = dt4 * 256 + tid;
    const size_t base = (size_t)b * TLEN + (size_t)c * LC;

    if (tid < 128) {
        const int row = tid >> 2, c4 = tid & 3;
        *(f32x4*)&sB[row][c4 * 4] =
            *(const f32x4*)&BC[(base + row) * (2 * DSTATE) + c4 * 4];
    } else {
        const int sj = tid - 128;
        const int row = sj >> 2, c4 = sj & 3;
        *(f32x4*)&sC[row][c4 * 4] =
            *(const f32x4*)&BC[(base + row) * (2 * DSTATE) + DSTATE + c4 * 4];
    }

    float A[DSTATE];
#pragma unroll
    for (int q = 0; q < 4; ++q) {
        f32x4 v = *(const f32x4*)&A_log[(size_t)d * DSTATE + q * 4];
        A[q * 4 + 0] = -__expf(v.x); A[q * 4 + 1] = -__expf(v.y);
        A[q * 4 + 2] = -__expf(v.z); A[q * 4 + 3] = -__expf(v.w);
    }
    const float Dp = D_param[d];

    float h[DSTATE];
    const size_t po = ps_addr((((size_t)c * BATCH + b) * DIM + d) * DSTATE);
#pragma unroll
    for (int q = 0; q < 4; ++q)
        *(f32x4*)&h[q * 4] = *(const f32x4*)&Hin[po + q * 4];
    __syncthreads();

    for (int t = 0; t < LC; ++t) {
        const float dtv = dt[(base + t) * DIM + d];
        const float xv  = x_in[(base + t) * DIM + d];
        const float zv  = xz[(base + t) * (2 * DIM) + DIM + d];
        const float dbx = dtv * xv;
        float y0 = 0.f, y1 = 0.f, y2 = 0.f, y3 = 0.f;
#pragma unroll
        for (int q = 0; q < 4; ++q) {
            float a0 = __expf(dtv * A[q * 4 + 0]);
            float a1 = __expf(dtv * A[q * 4 + 1]);
            float a2 = __expf(dtv * A[q * 4 + 2]);
            float a3 = __expf(dtv * A[q * 4 + 3]);
            h[q * 4 + 0] = fmaf(a0, h[q * 4 + 0], dbx * sB[t][q * 4 + 0]);
            h[q * 4 + 1] = fmaf(a1, h[q * 4 + 1], dbx * sB[t][q * 4 + 1]);
            h[q * 4 + 2] = fmaf(a2, h[q * 4 + 2], dbx * sB[t][q * 4 + 2]);
            h[q * 4 + 3] = fmaf(a3, h[q * 4 + 3], dbx * sB[t][q * 4 + 3]);
            y0 = fmaf(h[q * 4 + 0], sC[t][q * 4 + 0], y0);
            y1 = fmaf(h[q * 4 + 1], sC[t][q * 4 + 1], y1);
            y2 = fmaf(h[q * 4 + 2], sC[t][q * 4 + 2], y2);
            y3 = fmaf(h[q * 4 + 3], sC[t][q * 4 + 3], y3);
        }
        float y = (y0 + y1) + (y2 + y3) + Dp * xv;
        const float sig = 1.f / (1.f + __expf(-zv));
        const float yg = y * (zv * sig);
        unsigned short hv = f32_to_bf16(yg);
        yh[(base + t) * DIM + d] = hv;
        yl[(base + t) * DIM + d] = f32_to_bf16(yg - bf16_to_f32(hv));
    }
}

// ---------------------------------------------------------------------------
// Launch
// ---------------------------------------------------------------------------
extern "C" void kernel_launch(void* const* d_in, const int* in_sizes, int n_in,
                              void* d_out, int out_size, void* d_ws, size_t ws_size,
                              hipStream_t stream)
{
    const float* x      = (const float*)d_in[0];
    const float* W_in   = (const float*)d_in[1];
    const float* conv_w = (const float*)d_in[2];
    const float* conv_b = (const float*)d_in[3];
    const float* A_log  = (const float*)d_in[4];
    const float* D_par  = (const float*)d_in[5];
    const float* W_x    = (const float*)d_in[6];
    const float* W_dt   = (const float*)d_in[7];
    const float* b_dt   = (const float*)d_in[8];
    const float* W_out  = (const float*)d_in[9];
    float* out = (float*)d_out;

    const size_t BT = (size_t)BATCH * TLEN;          // 8192
    float* ws = (float*)d_ws;
    float* xz   = ws;                                // BT*2048 f32
    float* x_in = xz + BT * (2 * DIM);               // BT*1024 f32
    float* dtb  = x_in + BT * DIM;                   // BT*1024 f32
    float* BCb  = dtb + BT * DIM;                    // BT*32   f32

    unsigned short* bfAh = (unsigned short*)(BCb + BT * 2 * DSTATE);
    unsigned short* bfAl = bfAh + BT * DIM;
    unsigned short* WinTh = bfAl + BT * DIM;                 // 2048*1024
    unsigned short* WinTl = WinTh + (size_t)2048 * 1024;
    unsigned short* WdtTh = WinTl + (size_t)2048 * 1024;     // 1024*1024
    unsigned short* WdtTl = WdtTh + (size_t)1024 * 1024;
    unsigned short* WoutTh = WdtTl + (size_t)1024 * 1024;    // 1024*1024
    unsigned short* WoutTl = WoutTh + (size_t)1024 * 1024;

    // P/S chunk-scan scratch in dead x-half columns of xz (via ps_addr).
    float* Pb = xz;
    float* Sb = xz + (size_t)4096 * 2048;

    // 0) unified prep: weight transpose-splits + x split
    prep_kernel<<<12288, 256, 0, stream>>>(
        x, W_in, W_dt, W_out, bfAh, bfAl,
        WinTh, WinTl, WdtTh, WdtTl, WoutTh, WoutTl);

    // 1) xz = x @ W_in   (1024 blocks = 4/CU, balanced)
    gemm_bf16s<0><<<dim3(2048 / 128, BT / 128), 256, 0, stream>>>(
        bfAh, bfAl, WinTh, WinTl, nullptr, xz, (int)BT, 2 * DIM, DIM);

    // 2) conv + silu -> x_in f32 + bf16 hi/lo (overwrites Xh/Xl, now dead)
    conv_silu_kernel<<<(int)(BT * DIM / 1024), 256, 0, stream>>>(
        xz, conv_w, conv_b, x_in, bfAh, bfAl);

    // 3) dt = softplus(x_in @ W_dt + b_dt)   (512 blocks = 2/CU, balanced)
    gemm_bf16s<1><<<dim3(1024 / 128, BT / 128), 256, 0, stream>>>(
        bfAh, bfAl, WdtTh, WdtTl, b_dt, dtb, (int)BT, DIM, DIM);

    // 3b) BC = x_in @ W_x  (f32 dedicated kernel)
    bc_kernel<<<(int)(BT / 8), 256, 0, stream>>>(x_in, W_x, BCb);

    // 4) chunked parallel scan; pass C writes y hi/lo (over xin h/l, dead)
    {
        int grid_ac = BATCH * NC * (DIM / 256);      // 1024 blocks
        scan_pass_a<<<grid_ac, 256, 0, stream>>>(dtb, BCb, x_in, A_log, Pb, Sb);
        scan_pass_b<<<(BATCH * DIM * DSTATE) / 256, 256, 0, stream>>>(Pb, Sb);
        scan_pass_c<<<grid_ac, 256, 0, stream>>>(dtb, BCb, xz, A_log, D_par, Pb,
                                                 x_in, bfAh, bfAl);
    }

    // 5) out = y @ W_out   (512 blocks = 2/CU, balanced)
    gemm_bf16s<0><<<dim3(1024 / 128, BT / 128), 256, 0, stream>>>(
        bfAh, bfAl, WoutTh, WoutTl, nullptr, out, (int)BT, DIM, DIM);
}

// Round 8
// 510.291 us; speedup vs baseline: 1.1659x; 1.1659x over previous
//
#include <hip/hip_runtime.h>
#include <math.h>

#define DIM 1024
#define DSTATE 16
#define DCONV 4
#define BATCH 2
#define TLEN 4096
#define NC 128           // time chunks
#define LC (TLEN / NC)   // 32 steps per chunk

typedef short s16x4 __attribute__((ext_vector_type(4)));
typedef short s16x8 __attribute__((ext_vector_type(8)));
typedef float f32x4 __attribute__((ext_vector_type(4)));
typedef float f32x16 __attribute__((ext_vector_type(16)));

__device__ __forceinline__ unsigned short f32_to_bf16(float f) {
    unsigned int u = __float_as_uint(f);
    u += 0x7fffu + ((u >> 16) & 1u);
    return (unsigned short)(u >> 16);
}
__device__ __forceinline__ float bf16_to_f32(unsigned short s) {
    return __uint_as_float(((unsigned int)s) << 16);
}

__device__ __forceinline__ void async16(const void* g, void* l) {
    __builtin_amdgcn_global_load_lds(
        (const __attribute__((address_space(1))) void*)g,
        (__attribute__((address_space(3))) void*)l, 16, 0, 0);
}

// Strided index into dead x-half columns of xz (P/S chunk-scan scratch).
__device__ __forceinline__ size_t ps_addr(size_t i) {
    return ((i >> 10) << 11) | (i & 1023);
}

// ---------------------------------------------------------------------------
// Split-bf16 MFMA GEMM: C[M,N] = (Ah+Al)[M,K] @ (Bh+Bl)^T[N,K]
// Tile 128 x TN, BK=32, 256 threads (4 waves, 2x2), 32x32x16 MFMA.
// TN=128: wave tile 64x64 (2x2 of 32x32), LDS 32 KB, for large-N GEMMs.
// TN=64:  wave tile 64x32 (2x1 of 32x32), LDS 24 KB, doubles blocks/CU for
//         N=1024-class GEMMs (R7 post-mortem: 128x128 at 2 blocks/CU runs at
//         ~half efficiency — per-block barrier critical path not overlapped).
// 16 B LDS chunks XOR-swizzled by ((row>>1)&3).
// EPI: 0 = plain store (ldc=N), 1 = softplus(acc+bias[n]),
//      2 = combined: cols [0,1024) -> softplus+bias into C (ldc=DIM),
//                    cols [1024,1056) -> plain f32 into C2 (ldc=32),
//                    cols >= 1056    -> skip (zero-pad tiles).
// ---------------------------------------------------------------------------
template <int TN, int EPI>
__global__ __launch_bounds__(256) void gemm_bf16s(
    const unsigned short* __restrict__ Ah, const unsigned short* __restrict__ Al,
    const unsigned short* __restrict__ Bh, const unsigned short* __restrict__ Bl,
    const float* __restrict__ bias, float* __restrict__ C,
    float* __restrict__ C2, int M, int N, int K)
{
    constexpr int NT = TN / 64;            // 32-wide n-tiles per wave (2 or 1)
    __shared__ unsigned short sAh[128][32];
    __shared__ unsigned short sAl[128][32];
    __shared__ unsigned short sBh[TN][32];
    __shared__ unsigned short sBl[TN][32];

    const int tid  = threadIdx.x;
    const int lane = tid & 63;
    const int w    = tid >> 6;
    const int wm   = (w >> 1) * 64;
    const int wn   = (w & 1) * (TN / 2);
    const int m0   = blockIdx.y * 128;
    const int n0   = blockIdx.x * TN;

    f32x16 acc[2][NT];
#pragma unroll
    for (int i = 0; i < 2; ++i)
#pragma unroll
        for (int j = 0; j < NT; ++j)
#pragma unroll
            for (int r = 0; r < 16; ++r) acc[i][j][r] = 0.f;

    // Staging: lane l fills LDS row (w*16 + l/4), phys chunk (l&3).
    // Phys chunk p at row R holds global chunk p ^ ((R>>1)&3).
    const int srow  = w * 16 + (lane >> 2);
    const int skoff = (((lane & 3) ^ ((lane >> 3) & 3)) * 8);
    const size_t aRow0 = (size_t)(m0 + srow) * K;
    const size_t aRow1 = (size_t)(m0 + srow + 64) * K;
    const size_t bRow0 = (size_t)(n0 + srow) * K;
    const size_t bRow1 = (size_t)(n0 + srow + 64) * K;   // TN=128 only

    // Frag read (32x32x16): A[m = lane&31][k = (lane>>5)*8 + j].
    const int frow = lane & 31;
    const int fkh  = lane >> 5;
    const int fsw  = (lane >> 1) & 3;

    for (int k0 = 0; k0 < K; k0 += 32) {
        __syncthreads();
        async16(&Ah[aRow0 + k0 + skoff], &sAh[w * 16][0]);
        async16(&Ah[aRow1 + k0 + skoff], &sAh[64 + w * 16][0]);
        async16(&Al[aRow0 + k0 + skoff], &sAl[w * 16][0]);
        async16(&Al[aRow1 + k0 + skoff], &sAl[64 + w * 16][0]);
        async16(&Bh[bRow0 + k0 + skoff], &sBh[w * 16][0]);
        async16(&Bl[bRow0 + k0 + skoff], &sBl[w * 16][0]);
        if (TN == 128) {
            async16(&Bh[bRow1 + k0 + skoff], &sBh[(TN / 2) + w * 16][0]);
            async16(&Bl[bRow1 + k0 + skoff], &sBl[(TN / 2) + w * 16][0]);
        }
        __syncthreads();

#pragma unroll
        for (int ks = 0; ks < 2; ++ks) {
            const int pc = (((ks << 1) | fkh) ^ fsw) << 3;
            s16x8 fah[2], fal[2], fbh[NT], fbl[NT];
#pragma unroll
            for (int i = 0; i < 2; ++i) {
                fah[i] = *(const s16x8*)&sAh[wm + i * 32 + frow][pc];
                fal[i] = *(const s16x8*)&sAl[wm + i * 32 + frow][pc];
            }
#pragma unroll
            for (int i = 0; i < NT; ++i) {
                fbh[i] = *(const s16x8*)&sBh[wn + i * 32 + frow][pc];
                fbl[i] = *(const s16x8*)&sBl[wn + i * 32 + frow][pc];
            }
#pragma unroll
            for (int mt = 0; mt < 2; ++mt)
#pragma unroll
                for (int nt = 0; nt < NT; ++nt) {
                    acc[mt][nt] = __builtin_amdgcn_mfma_f32_32x32x16_bf16(
                        fah[mt], fbh[nt], acc[mt][nt], 0, 0, 0);
                    acc[mt][nt] = __builtin_amdgcn_mfma_f32_32x32x16_bf16(
                        fah[mt], fbl[nt], acc[mt][nt], 0, 0, 0);
                    acc[mt][nt] = __builtin_amdgcn_mfma_f32_32x32x16_bf16(
                        fal[mt], fbh[nt], acc[mt][nt], 0, 0, 0);
                }
        }
    }

    // C/D layout (32x32): col = lane&31, row = (reg&3) + 8*(reg>>2) + 4*(lane>>5)
    const int ecol  = lane & 31;
    const int erow4 = (lane >> 5) * 4;
#pragma unroll
    for (int mt = 0; mt < 2; ++mt)
#pragma unroll
        for (int nt = 0; nt < NT; ++nt) {
            const int colbase = n0 + wn + nt * 32;   // wave-uniform
            if (EPI == 2 && colbase >= 1024 + 2 * DSTATE) continue;
            const int col = colbase + ecol;
            if (EPI == 2 && colbase >= 1024) {
#pragma unroll
                for (int r = 0; r < 16; ++r) {
                    const int row = m0 + wm + mt * 32 + (r & 3) + 8 * (r >> 2) + erow4;
                    C2[(size_t)row * (2 * DSTATE) + (col - 1024)] = acc[mt][nt][r];
                }
            } else {
                const float bv = (EPI >= 1) ? bias[col] : 0.f;
                const int ldc = (EPI == 2) ? DIM : N;
#pragma unroll
                for (int r = 0; r < 16; ++r) {
                    const int row = m0 + wm + mt * 32 + (r & 3) + 8 * (r >> 2) + erow4;
                    float v = acc[mt][nt][r];
                    if (EPI >= 1) {
                        v += bv;
                        v = (v > 20.f) ? v : log1pf(__expf(v));
                    }
                    C[(size_t)row * ldc + col] = v;
                }
            }
        }
}

// ---------------------------------------------------------------------------
// Unified prep: weight transpose-splits + input x split, one launch.
// Blocks [0,2048): W_in; [2048,3072): W_dt; [3072,3104): W_x;
// [3104,4128): W_out; [4128,12320): x split (4 elems/thread).
// ---------------------------------------------------------------------------
__device__ __forceinline__ void tsplit(
    const float* __restrict__ W, unsigned short* __restrict__ Th,
    unsigned short* __restrict__ Tl, int Kdim, int Ndim, int bx, int by,
    int tid, float (*tile)[33])
{
    const int n0 = bx * 32;
    const int k0 = by * 32;
    const int tx = tid & 31;
    const int ty = tid >> 5;
    for (int r = ty; r < 32; r += 8)
        tile[r][tx] = W[(size_t)(k0 + r) * Ndim + n0 + tx];
    __syncthreads();
    for (int r = ty; r < 32; r += 8) {
        float v = tile[tx][r];
        unsigned short hv = f32_to_bf16(v);
        size_t o = (size_t)(n0 + r) * Kdim + k0 + tx;
        Th[o] = hv;
        Tl[o] = f32_to_bf16(v - bf16_to_f32(hv));
    }
}

__global__ __launch_bounds__(256) void prep_kernel(
    const float* __restrict__ x, const float* __restrict__ W_in,
    const float* __restrict__ W_dt, const float* __restrict__ W_x,
    const float* __restrict__ W_out,
    unsigned short* __restrict__ xh, unsigned short* __restrict__ xl,
    unsigned short* __restrict__ WinTh, unsigned short* __restrict__ WinTl,
    unsigned short* __restrict__ W2Th, unsigned short* __restrict__ W2Tl,
    unsigned short* __restrict__ WoutTh, unsigned short* __restrict__ WoutTl)
{
    __shared__ float tile[32][33];
    const int tid = threadIdx.x;
    const int blk = blockIdx.x;
    if (blk < 2048) {
        tsplit(W_in, WinTh, WinTl, 1024, 2048, blk & 63, blk >> 6, tid, tile);
    } else if (blk < 3072) {
        const int b2 = blk - 2048;
        tsplit(W_dt, W2Th, W2Tl, 1024, 1024, b2 & 31, b2 >> 5, tid, tile);
    } else if (blk < 3104) {
        tsplit(W_x, W2Th + (size_t)1024 * 1024, W2Tl + (size_t)1024 * 1024,
               1024, 32, 0, blk - 3072, tid, tile);
    } else if (blk < 4128) {
        const int b2 = blk - 3104;
        tsplit(W_out, WoutTh, WoutTl, 1024, 1024, b2 & 31, b2 >> 5, tid, tile);
    } else {
        const size_t i = ((size_t)(blk - 4128) * 256 + tid) * 4;
        f32x4 v = *(const f32x4*)&x[i];
        s16x4 h, l;
#pragma unroll
        for (int j = 0; j < 4; ++j) {
            unsigned short hv = f32_to_bf16(v[j]);
            h[j] = (short)hv;
            l[j] = (short)f32_to_bf16(v[j] - bf16_to_f32(hv));
        }
        *(s16x4*)&xh[i] = h;
        *(s16x4*)&xl[i] = l;
    }
}

// ---------------------------------------------------------------------------
// Depthwise causal conv (window 4) + bias + SiLU; 4 d-channels per thread;
// writes f32 + bf16 hi/lo.
// ---------------------------------------------------------------------------
__global__ __launch_bounds__(256) void conv_silu_kernel(
    const float* __restrict__ xz, const float* __restrict__ conv_w,
    const float* __restrict__ conv_b, float* __restrict__ x_in,
    unsigned short* __restrict__ xh, unsigned short* __restrict__ xl)
{
    const size_t idx4 = ((size_t)blockIdx.x * 256 + threadIdx.x) * 4;
    const int d = (int)(idx4 & (DIM - 1));
    const size_t bt = idx4 >> 10;
    const int t = (int)(bt & (TLEN - 1));

    f32x4 acc = *(const f32x4*)&conv_b[d];
    f32x4 w0 = *(const f32x4*)&conv_w[(d + 0) * DCONV];
    f32x4 w1 = *(const f32x4*)&conv_w[(d + 1) * DCONV];
    f32x4 w2 = *(const f32x4*)&conv_w[(d + 2) * DCONV];
    f32x4 w3 = *(const f32x4*)&conv_w[(d + 3) * DCONV];
#pragma unroll
    for (int k = 0; k < DCONV; ++k) {
        const int tt = t - (DCONV - 1) + k;
        if (tt >= 0) {
            f32x4 xv = *(const f32x4*)&xz[(bt - (DCONV - 1) + k) * (2 * DIM) + d];
            acc.x = fmaf(xv.x, w0[k], acc.x);
            acc.y = fmaf(xv.y, w1[k], acc.y);
            acc.z = fmaf(xv.z, w2[k], acc.z);
            acc.w = fmaf(xv.w, w3[k], acc.w);
        }
    }
    f32x4 s;
    s16x4 h, l;
#pragma unroll
    for (int j = 0; j < 4; ++j) {
        s[j] = acc[j] / (1.f + __expf(-acc[j]));
        unsigned short hv = f32_to_bf16(s[j]);
        h[j] = (short)hv;
        l[j] = (short)f32_to_bf16(s[j] - bf16_to_f32(hv));
    }
    *(f32x4*)&x_in[idx4] = s;
    *(s16x4*)&xh[idx4] = h;
    *(s16x4*)&xl[idx4] = l;
}

// ---------------------------------------------------------------------------
// Scan pass A: one lane per (b,d); h[16] in VGPRs; local scan from h=0.
// Stores S = h_local_end[16], P = exp(A_n * sum_dt). B staged in LDS.
// ---------------------------------------------------------------------------
__global__ __launch_bounds__(256) void scan_pass_a(
    const float* __restrict__ dt, const float* __restrict__ BC,
    const float* __restrict__ x_in, const float* __restrict__ A_log,
    float* __restrict__ Pb, float* __restrict__ Sb)
{
    __shared__ float sB[LC][DSTATE];
    const int tid = threadIdx.x;
    int blk = blockIdx.x;
    const int dt4 = blk & 3;  blk >>= 2;
    const int c = blk & (NC - 1); blk >>= 7;
    const int b = blk;
    const int d = dt4 * 256 + tid;
    const size_t base = (size_t)b * TLEN + (size_t)c * LC;

    if (tid < LC * DSTATE / 4) {
        const int row = tid >> 2, c4 = tid & 3;
        *(f32x4*)&sB[row][c4 * 4] =
            *(const f32x4*)&BC[(base + row) * (2 * DSTATE) + c4 * 4];
    }

    float A[DSTATE];
#pragma unroll
    for (int q = 0; q < 4; ++q) {
        f32x4 v = *(const f32x4*)&A_log[(size_t)d * DSTATE + q * 4];
        A[q * 4 + 0] = -__expf(v.x); A[q * 4 + 1] = -__expf(v.y);
        A[q * 4 + 2] = -__expf(v.z); A[q * 4 + 3] = -__expf(v.w);
    }
    __syncthreads();

    float h[DSTATE];
#pragma unroll
    for (int n = 0; n < DSTATE; ++n) h[n] = 0.f;
    float sdt = 0.f;

    for (int t = 0; t < LC; ++t) {
        const float dtv = dt[(base + t) * DIM + d];
        const float xv  = x_in[(base + t) * DIM + d];
        sdt += dtv;
        const float dbx = dtv * xv;
#pragma unroll
        for (int n = 0; n < DSTATE; ++n) {
            const float a = __expf(dtv * A[n]);
            h[n] = fmaf(a, h[n], dbx * sB[t][n]);
        }
    }

    const size_t po = ps_addr((((size_t)c * BATCH + b) * DIM + d) * DSTATE);
#pragma unroll
    for (int q = 0; q < 4; ++q) {
        f32x4 pv;
        pv.x = __expf(A[q * 4 + 0] * sdt);
        pv.y = __expf(A[q * 4 + 1] * sdt);
        pv.z = __expf(A[q * 4 + 2] * sdt);
        pv.w = __expf(A[q * 4 + 3] * sdt);
        *(f32x4*)&Pb[po + q * 4] = pv;
        *(f32x4*)&Sb[po + q * 4] = *(f32x4*)&h[q * 4];
    }
}

// ---------------------------------------------------------------------------
// Scan pass B: per (b,d,n): sequential combine over NC chunks.
// ---------------------------------------------------------------------------
__global__ __launch_bounds__(256) void scan_pass_b(
    float* __restrict__ Pb, const float* __restrict__ Sb)
{
    const size_t idx = (size_t)blockIdx.x * 256 + threadIdx.x;  // B*DIM*16
    float h = 0.f;
#pragma unroll 4
    for (int c = 0; c < NC; ++c) {
        const size_t o = (size_t)c * (BATCH * DIM * DSTATE) + idx;
        const size_t a = ps_addr(o);
        const float p = Pb[a];
        const float s = Sb[a];
        Pb[a] = h;
        h = fmaf(p, h, s);
    }
}

// ---------------------------------------------------------------------------
// Scan pass C: one lane per (b,d); seeded local scan; y = sum_n h*C + D*x;
// fused z-gate; writes y as bf16 hi/lo. B,C staged in LDS.
// ---------------------------------------------------------------------------
__global__ __launch_bounds__(256) void scan_pass_c(
    const float* __restrict__ dt, const float* __restrict__ BC,
    const float* __restrict__ xz, const float* __restrict__ A_log,
    const float* __restrict__ D_param, const float* __restrict__ Hin,
    const float* __restrict__ x_in,
    unsigned short* __restrict__ yh, unsigned short* __restrict__ yl)
{
    __shared__ float sB[LC][DSTATE];
    __shared__ float sC[LC][DSTATE];
    const int tid = threadIdx.x;
    int blk = blockIdx.x;
    const int dt4 = blk & 3;  blk >>= 2;
    const int c = blk & (NC - 1); blk >>= 7;
    const int b = blk;
    const int d = dt4 * 256 + tid;
    const size_t base = (size_t)b * TLEN + (size_t)c * LC;

    if (tid < 128) {
        const int row = tid >> 2, c4 = tid & 3;
        *(f32x4*)&sB[row][c4 * 4] =
            *(const f32x4*)&BC[(base + row) * (2 * DSTATE) + c4 * 4];
    } else {
        const int sj = tid - 128;
        const int row = sj >> 2, c4 = sj & 3;
        *(f32x4*)&sC[row][c4 * 4] =
            *(const f32x4*)&BC[(base + row) * (2 * DSTATE) + DSTATE + c4 * 4];
    }

    float A[DSTATE];
#pragma unroll
    for (int q = 0; q < 4; ++q) {
        f32x4 v = *(const f32x4*)&A_log[(size_t)d * DSTATE + q * 4];
        A[q * 4 + 0] = -__expf(v.x); A[q * 4 + 1] = -__expf(v.y);
        A[q * 4 + 2] = -__expf(v.z); A[q * 4 + 3] = -__expf(v.w);
    }
    const float Dp = D_param[d];

    float h[DSTATE];
    const size_t po = ps_addr((((size_t)c * BATCH + b) * DIM + d) * DSTATE);
#pragma unroll
    for (int q = 0; q < 4; ++q)
        *(f32x4*)&h[q * 4] = *(const f32x4*)&Hin[po + q * 4];
    __syncthreads();

    for (int t = 0; t < LC; ++t) {
        const float dtv = dt[(base + t) * DIM + d];
        const float xv  = x_in[(base + t) * DIM + d];
        const float zv  = xz[(base + t) * (2 * DIM) + DIM + d];
        const float dbx = dtv * xv;
        float y0 = 0.f, y1 = 0.f, y2 = 0.f, y3 = 0.f;
#pragma unroll
        for (int q = 0; q < 4; ++q) {
            float a0 = __expf(dtv * A[q * 4 + 0]);
            float a1 = __expf(dtv * A[q * 4 + 1]);
            float a2 = __expf(dtv * A[q * 4 + 2]);
            float a3 = __expf(dtv * A[q * 4 + 3]);
            h[q * 4 + 0] = fmaf(a0, h[q * 4 + 0], dbx * sB[t][q * 4 + 0]);
            h[q * 4 + 1] = fmaf(a1, h[q * 4 + 1], dbx * sB[t][q * 4 + 1]);
            h[q * 4 + 2] = fmaf(a2, h[q * 4 + 2], dbx * sB[t][q * 4 + 2]);
            h[q * 4 + 3] = fmaf(a3, h[q * 4 + 3], dbx * sB[t][q * 4 + 3]);
            y0 = fmaf(h[q * 4 + 0], sC[t][q * 4 + 0], y0);
            y1 = fmaf(h[q * 4 + 1], sC[t][q * 4 + 1], y1);
            y2 = fmaf(h[q * 4 + 2], sC[t][q * 4 + 2], y2);
            y3 = fmaf(h[q * 4 + 3], sC[t][q * 4 + 3], y3);
        }
        float y = (y0 + y1) + (y2 + y3) + Dp * xv;
        const float sig = 1.f / (1.f + __expf(-zv));
        const float yg = y * (zv * sig);
        unsigned short hv = f32_to_bf16(yg);
        yh[(base + t) * DIM + d] = hv;
        yl[(base + t) * DIM + d] = f32_to_bf16(yg - bf16_to_f32(hv));
    }
}

// ---------------------------------------------------------------------------
// Launch
// ---------------------------------------------------------------------------
extern "C" void kernel_launch(void* const* d_in, const int* in_sizes, int n_in,
                              void* d_out, int out_size, void* d_ws, size_t ws_size,
                              hipStream_t stream)
{
    const float* x      = (const float*)d_in[0];
    const float* W_in   = (const float*)d_in[1];
    const float* conv_w = (const float*)d_in[2];
    const float* conv_b = (const float*)d_in[3];
    const float* A_log  = (const float*)d_in[4];
    const float* D_par  = (const float*)d_in[5];
    const float* W_x    = (const float*)d_in[6];
    const float* W_dt   = (const float*)d_in[7];
    const float* b_dt   = (const float*)d_in[8];
    const float* W_out  = (const float*)d_in[9];
    float* out = (float*)d_out;

    const size_t BT = (size_t)BATCH * TLEN;          // 8192
    float* ws = (float*)d_ws;
    float* xz   = ws;                                // BT*2048 f32
    float* x_in = xz + BT * (2 * DIM);               // BT*1024 f32
    float* dtb  = x_in + BT * DIM;                   // BT*1024 f32
    float* BCb  = dtb + BT * DIM;                    // BT*32   f32

    unsigned short* bfAh = (unsigned short*)(BCb + BT * 2 * DSTATE);
    unsigned short* bfAl = bfAh + BT * DIM;
    unsigned short* WinTh = bfAl + BT * DIM;                 // 2048*1024
    unsigned short* WinTl = WinTh + (size_t)2048 * 1024;
    unsigned short* W2Th  = WinTl + (size_t)2048 * 1024;     // 1152*1024 (dt|Wx|pad)
    unsigned short* W2Tl  = W2Th + (size_t)1152 * 1024;
    unsigned short* WoutTh = W2Tl + (size_t)1152 * 1024;     // 1024*1024
    unsigned short* WoutTl = WoutTh + (size_t)1024 * 1024;

    // P/S chunk-scan scratch in dead x-half columns of xz (via ps_addr).
    float* Pb = xz;
    float* Sb = xz + (size_t)4096 * 2048;

    // 0) unified prep: weight transpose-splits + x split
    prep_kernel<<<12320, 256, 0, stream>>>(
        x, W_in, W_dt, W_x, W_out, bfAh, bfAl,
        WinTh, WinTl, W2Th, W2Tl, WoutTh, WoutTl);
    // pad rows 1056..1151 of W2T stay 0xAA-poisoned: tiny finite bf16 values,
    // their output tiles are skip-stored in the EPI=2 epilogue.

    // 1) xz = x @ W_in   (TN=128: 1024 blocks = 4/CU)
    gemm_bf16s<128, 0><<<dim3(2048 / 128, BT / 128), 256, 0, stream>>>(
        bfAh, bfAl, WinTh, WinTl, nullptr, xz, nullptr, (int)BT, 2 * DIM, DIM);

    // 2) conv + silu -> x_in f32 + bf16 hi/lo (overwrites Xh/Xl, now dead)
    conv_silu_kernel<<<(int)(BT * DIM / 1024), 256, 0, stream>>>(
        xz, conv_w, conv_b, x_in, bfAh, bfAl);

    // 3) dt = softplus(x_in @ W_dt + b_dt) AND BC = x_in @ W_x (fused, TN=64:
    //    1152 blocks = 4.5/CU vs 2.25 at TN=128)
    gemm_bf16s<64, 2><<<dim3(1152 / 64, BT / 128), 256, 0, stream>>>(
        bfAh, bfAl, W2Th, W2Tl, b_dt, dtb, BCb, (int)BT, 1152, DIM);

    // 4) chunked parallel scan; pass C writes y hi/lo (over xin h/l, dead)
    {
        int grid_ac = BATCH * NC * (DIM / 256);      // 1024 blocks
        scan_pass_a<<<grid_ac, 256, 0, stream>>>(dtb, BCb, x_in, A_log, Pb, Sb);
        scan_pass_b<<<(BATCH * DIM * DSTATE) / 256, 256, 0, stream>>>(Pb, Sb);
        scan_pass_c<<<grid_ac, 256, 0, stream>>>(dtb, BCb, xz, A_log, D_par, Pb,
                                                 x_in, bfAh, bfAl);
    }

    // 5) out = y @ W_out   (TN=64: 1024 blocks = 4/CU)
    gemm_bf16s<64, 0><<<dim3(1024 / 64, BT / 128), 256, 0, stream>>>(
        bfAh, bfAl, WoutTh, WoutTl, nullptr, out, nullptr, (int)BT, DIM, DIM);
}